// Round 8
// baseline (215.195 us; speedup 1.0000x reference)
//
#include <hip/hip_runtime.h>
#include <stdint.h>

// Problem constants
#define CC    1024
#define EE    320
#define KN    640         // G*E
#define DD    256
#define MTOT  16384       // B*T
#define NBLK  640         // GEMM grid
#define OUT4  2097152     // output float4 count

typedef __attribute__((ext_vector_type(8))) short short8;
typedef __attribute__((ext_vector_type(4))) float f32x4;

__device__ __forceinline__ unsigned int f32_orderable(float x) {
    unsigned int b = __float_as_uint(x);
    return (b & 0x80000000u) ? ~b : (b | 0x80000000u);
}

// 8 fp32 -> bf16 hi (round-half-up) + lo (bf16 of exact residual). err ~2^-17|x|.
__device__ __forceinline__ void cvt_hilo8(float4 a, float4 b, short8& hi, short8& lo) {
    float x[8] = {a.x, a.y, a.z, a.w, b.x, b.y, b.z, b.w};
#pragma unroll
    for (int j = 0; j < 8; j++) {
        unsigned int u  = __float_as_uint(x[j]);
        unsigned int v  = u + 0x8000u;
        float hif       = __uint_as_float(v & 0xFFFF0000u);
        float lof       = x[j] - hif;                 // exact in fp32
        unsigned int lu = __float_as_uint(lof) + 0x8000u;
        hi[j] = (short)(v >> 16);
        lo[j] = (short)(lu >> 16);
    }
}

__device__ __forceinline__ void gload_lds16(const void* g, void* l) {
    __builtin_amdgcn_global_load_lds(
        (const __attribute__((address_space(1))) unsigned int*)g,
        (__attribute__((address_space(3))) unsigned int*)l,
        16, 0, 0);
}

__global__ void init_slots_kernel(unsigned long long* __restrict__ slots) {
    if (threadIdx.x < 17) slots[threadIdx.x] = 0ull;
}

// ------------------- fused convert + zero-fill + slot init -------------------
// Fragment-major layout (both A2F from X and B2F from W):
//   unit = rowTile*32 + kc  (rowTile = row/16, kc = k/32)
//   buf[unit*1024 + lane*8 + j]       = bf16_hi of M[rowTile*16 + (lane&15)][kc*32 + (lane>>4)*8 + j]
//   buf[unit*1024 + 512 + lane*8 + j] = bf16_lo
// -> a tile-chunk (hi+lo) is 2KB CONTIGUOUS: global_load_lds stages it verbatim,
//    and frag ds_read_b128 at lane*16B is the canonical conflict-free pattern.
__global__ __launch_bounds__(256)
void convert_kernel(const float* __restrict__ X, const float* __restrict__ W,
                    unsigned short* __restrict__ A2F, unsigned short* __restrict__ B2F,
                    unsigned long long* __restrict__ slots, float* __restrict__ out) {
    const int bid = blockIdx.x;
    const int tid = threadIdx.x;
    // zero-fill share of the output (8512 blocks x 256 thr >= 2,097,152 float4s)
    {
        int zidx = bid * 256 + tid;
        f32x4 z = {0.f, 0.f, 0.f, 0.f};
        if (zidx < OUT4) __builtin_nontemporal_store(z, (f32x4*)out + zidx);
    }
    const int lane = tid & 63;
    if (bid < 8192) {                      // X: units = 1024 mb x 32 kc
        int unit = bid * 4 + (tid >> 6);
        int mb = unit >> 5, kc = unit & 31;
        int row = mb * 16 + (lane & 15);
        int col = kc * 32 + ((lane >> 4) << 3);
        const float* p = X + (size_t)row * CC + col;
        float4 v0 = *(const float4*)p;
        float4 v1 = *(const float4*)(p + 4);
        short8 hi, lo;
        cvt_hilo8(v0, v1, hi, lo);
        size_t base = (size_t)unit * 1024 + lane * 8;
        *(short8*)(A2F + base)       = hi;
        *(short8*)(A2F + base + 512) = lo;
    } else {                               // W: units = 40 nb x 32 kc -> 320 blocks
        if (bid == 8192 && tid < 17) slots[tid] = 0ull;   // 16 slots + counter
        int unit = (bid - 8192) * 4 + (tid >> 6);         // 0..1279
        int nb = unit >> 5, kc = unit & 31;
        int row = nb * 16 + (lane & 15);
        int col = kc * 32 + ((lane >> 4) << 3);
        const float* p = W + (size_t)row * CC + col;
        float4 v0 = *(const float4*)p;
        float4 v1 = *(const float4*)(p + 4);
        short8 hi, lo;
        cvt_hilo8(v0, v1, hi, lo);
        size_t base = (size_t)unit * 1024 + lane * 8;
        *(short8*)(B2F + base)       = hi;
        *(short8*)(B2F + base + 512) = lo;
    }
}

// ------------------- MFMA GEMM + fused argmax + scatter -------------------
// C = X*W^T via split-bf16 (ah*bh + al*bh + ah*bl).
// A and B both staged fragment-major through double-buffered LDS (16KB+16KB per
// K=32 iter) via global_load_lds: L2 traffic deduped (each byte enters the CU once),
// frag reads are contiguous-per-lane ds_read_b128 (conflict-free).
// One barrier per iter; staging for it+1 issued ~930 MFMA-cycles before its drain.
__global__ __launch_bounds__(256, 2)
void gemm_argmax_mfma(const unsigned short* __restrict__ A2F,
                      const unsigned short* __restrict__ B2F,
                      const float* __restrict__ bias,
                      const float* __restrict__ codebook,
                      float* __restrict__ out,
                      unsigned long long* __restrict__ slots,
                      unsigned int* __restrict__ counter) {
    __shared__ unsigned short As[2][8192];   // [buf]: 8 tiles x 2KB (hi|lo)
    __shared__ unsigned short Bs[2][8192];
    __shared__ unsigned long long red[4];
    __shared__ unsigned int done_s;
    __shared__ unsigned long long s16[16];

    const int tid  = threadIdx.x;
    const int lane = tid & 63;
    const int wave = tid >> 6;

    // XCD swizzle: one XCD covers 16 m-tiles x all 5 n-tiles (n fastest) -> A2F L2 reuse.
    const int l   = blockIdx.x;        // 0..639
    const int xcd = l & 7;
    const int w   = l >> 3;
    const int mt  = xcd * 16 + w / 5;
    const int nt  = w % 5;
    const int m0 = mt * 128;
    const int n0 = nt * 128;

    const int wm = (wave >> 1) * 64;
    const int wn = (wave & 1) * 64;

    // staging sources: wave stages A tiles {2w,2w+1} and B tiles {2w,2w+1} of the chunk.
    // per-lane global pointer = unit base + lane*8 shorts (identity copy to LDS).
    const unsigned short* a_src[2];
    const unsigned short* b_src[2];
#pragma unroll
    for (int c = 0; c < 2; c++) {
        int t = wave * 2 + c;
        a_src[c] = A2F + ((size_t)((m0 >> 4) + t) * 32) * 1024 + lane * 8;
        b_src[c] = B2F + ((size_t)((n0 >> 4) + t) * 32) * 1024 + lane * 8;
    }

    // frag read offsets (shorts): tile*1024 + part*512 + lane*8
    const int afo = ((wave >> 1) * 4) * 1024 + lane * 8;
    const int bfo = ((wave & 1) * 4) * 1024 + lane * 8;

    f32x4 acc[4][4] = {};

#define STAGE(BUF, KC)                                                           \
    {                                                                            \
        _Pragma("unroll")                                                        \
        for (int c = 0; c < 2; c++) {                                            \
            int t = wave * 2 + c;                                                \
            const unsigned short* ap = a_src[c] + (KC) * 1024;                   \
            const unsigned short* bp = b_src[c] + (KC) * 1024;                   \
            gload_lds16(ap,       (char*)As[BUF] + t * 2048);                    \
            gload_lds16(ap + 512, (char*)As[BUF] + t * 2048 + 1024);             \
            gload_lds16(bp,       (char*)Bs[BUF] + t * 2048);                    \
            gload_lds16(bp + 512, (char*)Bs[BUF] + t * 2048 + 1024);             \
        }                                                                        \
    }

    STAGE(0, 0)                          // prologue

    for (int it = 0; it < 32; it++) {
        const int buf = it & 1;
        __syncthreads();                 // chunk(buf) staged (issued ~1 iter ago); buf^1 reads done
        if (it < 31) STAGE(buf ^ 1, it + 1)

        short8 ah[4], al[4], bh[4], bl[4];
#pragma unroll
        for (int t = 0; t < 4; t++) {
            ah[t] = *(const short8*)&As[buf][afo + t * 1024];
            al[t] = *(const short8*)&As[buf][afo + t * 1024 + 512];
            bh[t] = *(const short8*)&Bs[buf][bfo + t * 1024];
            bl[t] = *(const short8*)&Bs[buf][bfo + t * 1024 + 512];
        }
#pragma unroll
        for (int ti = 0; ti < 4; ti++)
#pragma unroll
            for (int tj = 0; tj < 4; tj++)
                acc[ti][tj] = __builtin_amdgcn_mfma_f32_16x16x32_bf16(ah[ti], bh[tj], acc[ti][tj], 0, 0, 0);
#pragma unroll
        for (int ti = 0; ti < 4; ti++)
#pragma unroll
            for (int tj = 0; tj < 4; tj++)
                acc[ti][tj] = __builtin_amdgcn_mfma_f32_16x16x32_bf16(al[ti], bh[tj], acc[ti][tj], 0, 0, 0);
#pragma unroll
        for (int ti = 0; ti < 4; ti++)
#pragma unroll
            for (int tj = 0; tj < 4; tj++)
                acc[ti][tj] = __builtin_amdgcn_mfma_f32_16x16x32_bf16(ah[ti], bl[tj], acc[ti][tj], 0, 0, 0);
    }
#undef STAGE

    // ---- fused argmax epilogue ----
    // C/D layout (16x16x32): col = lane&15, row = (lane>>4)*4 + reg
    float bias4[4];
#pragma unroll
    for (int tj = 0; tj < 4; tj++) bias4[tj] = bias[n0 + wn + tj * 16 + (lane & 15)];

    unsigned long long best = 0ull;
#pragma unroll
    for (int ti = 0; ti < 4; ti++) {
#pragma unroll
        for (int r = 0; r < 4; r++) {
            int m  = m0 + wm + ti * 16 + (lane >> 4) * 4 + r;
            int tl = m & 1023;
#pragma unroll
            for (int tj = 0; tj < 4; tj++) {
                int n = n0 + wn + tj * 16 + (lane & 15);
                float v = acc[ti][tj][r] + bias4[tj];
                unsigned int c = (unsigned int)(tl * KN + n);
                unsigned long long p =
                    ((unsigned long long)f32_orderable(v) << 32) |
                    (unsigned long long)(~c);
                if (p > best) best = p;
            }
        }
    }
#pragma unroll
    for (int off = 32; off > 0; off >>= 1) {
        unsigned long long o = __shfl_down(best, off, 64);
        if (o > best) best = o;
    }
    if (lane == 0) red[wave] = best;
    __syncthreads();
    if (tid == 0) {
        unsigned long long b = red[0];
        for (int wv = 1; wv < 4; wv++) if (red[wv] > b) b = red[wv];
        atomicMax(slots + (m0 >> 10), b);
        __threadfence();
        done_s = atomicAdd(counter, 1u);
    }
    __syncthreads();

    // ---- last block scatters the 16 codebook rows ----
    if (done_s == NBLK - 1) {
        if (tid < 16) s16[tid] = atomicAdd(slots + tid, 0ull);   // coherent cross-XCD read
        __syncthreads();
        int rr  = tid >> 4;
        int seg = tid & 15;
        unsigned long long p = s16[rr];
        unsigned int c = ~(unsigned int)(p & 0xFFFFFFFFull);
        int tl = (int)(c / KN);
        int kg = (int)(c % KN);
        int b  = rr >> 1, h = rr & 1;
        int nstar = b * 2048 + h * 1024 + tl;
        int g = kg / EE;
        const float4* src = (const float4*)(codebook + (size_t)kg * DD) + seg * 4;
        float4* dst = (float4*)(out + (size_t)nstar * 512 + (size_t)g * DD) + seg * 4;
#pragma unroll
        for (int j = 0; j < 4; j++) dst[j] = src[j];
    }
}

// ------------------- fallback-only kernels (ws too small; not used in practice) ------------
__global__ __launch_bounds__(256)
void zs_kernel(const unsigned long long* __restrict__ slots,
               const float* __restrict__ codebook,
               float4* __restrict__ out4) {
    int i4 = blockIdx.x * 256 + threadIdx.x;
    int n  = i4 >> 7;
    int c4 = i4 & 127;
    int b  = n >> 11;
    int h  = (n >> 10) & 1;
    unsigned long long p = slots[b * 2 + h];
    unsigned int c = ~(unsigned int)(p & 0xFFFFFFFFull);
    int tl = (int)(c / KN);
    int kg = (int)(c % KN);
    int nstar = b * 2048 + h * 1024 + tl;
    int g = kg / EE;
    float4 v = make_float4(0.f, 0.f, 0.f, 0.f);
    if (n == nstar && (c4 >> 6) == g)
        v = ((const float4*)codebook)[kg * 64 + (c4 & 63)];
    out4[i4] = v;
}

#define BM 128
#define BN 64
#define BK 32
#define LDA (BM + 4)
#define LDB (BN + 4)

__global__ __launch_bounds__(128)
void gemm_argmax_f32(const float* __restrict__ X, const float* __restrict__ W,
                     const float* __restrict__ bias,
                     unsigned long long* __restrict__ slots) {
    __shared__ float Asf[BK][LDA];
    __shared__ float Bsf[BK][LDB];
    const int tid = threadIdx.x;
    const int m0 = blockIdx.y * BM;
    const int n0 = blockIdx.x * BN;
    const int tx = tid & 7, ty = tid >> 3;
    float acc[8][8];
#pragma unroll
    for (int i = 0; i < 8; i++)
#pragma unroll
        for (int j = 0; j < 8; j++) acc[i][j] = 0.0f;
    const int lm = tid >> 3, lk = (tid & 7) * 4;
    const float* Xb = X + (size_t)m0 * CC;
    const float* Wb = W + (size_t)n0 * CC;
    for (int k0 = 0; k0 < CC; k0 += BK) {
#pragma unroll
        for (int r = 0; r < 8; r++) {
            int m = r * 16 + lm;
            float4 v = *(const float4*)(Xb + (size_t)m * CC + k0 + lk);
            Asf[lk + 0][m] = v.x; Asf[lk + 1][m] = v.y; Asf[lk + 2][m] = v.z; Asf[lk + 3][m] = v.w;
        }
#pragma unroll
        for (int r = 0; r < 4; r++) {
            int m = r * 16 + lm;
            float4 v = *(const float4*)(Wb + (size_t)m * CC + k0 + lk);
            Bsf[lk + 0][m] = v.x; Bsf[lk + 1][m] = v.y; Bsf[lk + 2][m] = v.z; Bsf[lk + 3][m] = v.w;
        }
        __syncthreads();
#pragma unroll
        for (int kk = 0; kk < BK; kk++) {
            float4 a0 = *(const float4*)&Asf[kk][ty * 8];
            float4 a1 = *(const float4*)&Asf[kk][ty * 8 + 4];
            float4 b0 = *(const float4*)&Bsf[kk][tx * 8];
            float4 b1 = *(const float4*)&Bsf[kk][tx * 8 + 4];
            float a[8] = {a0.x, a0.y, a0.z, a0.w, a1.x, a1.y, a1.z, a1.w};
            float b[8] = {b0.x, b0.y, b0.z, b0.w, b1.x, b1.y, b1.z, b1.w};
#pragma unroll
            for (int i = 0; i < 8; i++)
#pragma unroll
                for (int j = 0; j < 8; j++) acc[i][j] = fmaf(a[i], b[j], acc[i][j]);
        }
        __syncthreads();
    }
    unsigned long long best = 0ull;
#pragma unroll
    for (int i = 0; i < 8; i++) {
        int mg = m0 + ty * 8 + i;
        int tl = mg & 1023;
#pragma unroll
        for (int j = 0; j < 8; j++) {
            int kg = n0 + tx * 8 + j;
            float v = acc[i][j] + bias[kg];
            unsigned int c = (unsigned int)(tl * KN + kg);
            unsigned long long p = ((unsigned long long)f32_orderable(v) << 32) |
                                   (unsigned long long)(~c);
            if (p > best) best = p;
        }
    }
#pragma unroll
    for (int off = 32; off > 0; off >>= 1) {
        unsigned long long o = __shfl_down(best, off, 64);
        if (o > best) best = o;
    }
    __shared__ unsigned long long red2[2];
    if ((tid & 63) == 0) red2[tid >> 6] = best;
    __syncthreads();
    if (tid == 0) {
        unsigned long long b0 = red2[0], b1 = red2[1];
        atomicMax(slots + (m0 >> 10), b0 > b1 ? b0 : b1);
    }
}

extern "C" void kernel_launch(void* const* d_in, const int* in_sizes, int n_in,
                              void* d_out, int out_size, void* d_ws, size_t ws_size,
                              hipStream_t stream) {
    const float* X        = (const float*)d_in[0];  // (8,2048,1024)
    const float* W        = (const float*)d_in[1];  // (640,1024)
    const float* bias     = (const float*)d_in[2];  // (640,)
    const float* codebook = (const float*)d_in[3];  // (640,256)
    float* out = (float*)d_out;                     // (8,2048,512) fp32

    unsigned long long* slots = (unsigned long long*)d_ws;   // [0..15] slots, [16] counter
    unsigned int* counter = (unsigned int*)(slots + 16);
    const size_t A_off   = 256;
    const size_t A_bytes = (size_t)MTOT * CC * 2 * 2;   // 67,108,864 (hi+lo fragment-major)
    const size_t B_off   = A_off + A_bytes;
    const size_t B_bytes = (size_t)KN * CC * 2 * 2;     // 2,621,440
    const size_t need = B_off + B_bytes;

    if (ws_size >= need) {
        unsigned short* A2F = (unsigned short*)((char*)d_ws + A_off);
        unsigned short* B2F = (unsigned short*)((char*)d_ws + B_off);
        hipLaunchKernelGGL(convert_kernel, dim3(8192 + 320), dim3(256), 0, stream,
                           X, W, A2F, B2F, slots, out);
        hipLaunchKernelGGL(gemm_argmax_mfma, dim3(NBLK), dim3(256), 0, stream,
                           A2F, B2F, bias, codebook, out, slots, counter);
    } else {
        hipLaunchKernelGGL(init_slots_kernel, dim3(1), dim3(64), 0, stream, slots);
        hipLaunchKernelGGL(gemm_argmax_f32, dim3(KN / BN, MTOT / BM), dim3(128), 0, stream,
                           X, W, bias, slots);
        hipLaunchKernelGGL(zs_kernel, dim3(OUT4 / 256), dim3(256), 0, stream,
                           slots, codebook, (float4*)out);
    }
}

// Round 9
// 154.319 us; speedup vs baseline: 1.3945x; 1.3945x over previous
//
#include <hip/hip_runtime.h>
#include <stdint.h>

// Problem constants
#define CC    1024
#define EE    320
#define KN    640         // G*E
#define DD    256
#define MTOT  16384       // B*T
#define NBLK  640         // GEMM grid
#define OUT4  2097152     // output float4 count
#define MARGIN 2.0f       // candidate gate: 15 sigma of hi*hi dropped-term error

typedef __attribute__((ext_vector_type(8))) short short8;
typedef __attribute__((ext_vector_type(4))) float f32x4;

__device__ __forceinline__ unsigned int f32_orderable(float x) {
    unsigned int b = __float_as_uint(x);
    return (b & 0x80000000u) ? ~b : (b | 0x80000000u);
}

__device__ __forceinline__ unsigned short bf16_rne(float x) {
    unsigned int u = __float_as_uint(x);
    return (unsigned short)((u + 0x7FFFu + ((u >> 16) & 1u)) >> 16);
}

__global__ void init_slots_kernel(unsigned long long* __restrict__ slots) {
    if (threadIdx.x < 17) slots[threadIdx.x] = 0ull;
}

// ------------------- fused convert (hi-only) + zero-fill + slot init -------------------
// Fragment-major hi-only layout (A2F from X, B2F from W):
//   unit = rowTile*32 + kc   (rowTile = row/16, kc = k/32)
//   buf[unit*512 + lane*8 + j] = bf16_hi of M[rowTile*16 + (lane&15)][kc*32 + (lane>>4)*8 + j]
// -> GEMM frag load = base + lane*16B (coalesced 1KB/wave, exact 16x16x32 operand layout).
__global__ __launch_bounds__(256)
void convert_kernel(const float* __restrict__ X, const float* __restrict__ W,
                    unsigned short* __restrict__ A2F, unsigned short* __restrict__ B2F,
                    unsigned long long* __restrict__ slots, float* __restrict__ out) {
    const int bid = blockIdx.x;
    const int tid = threadIdx.x;
    {   // zero-fill share of output (blocks 0..8191 cover all 2,097,152 float4s)
        int zidx = bid * 256 + tid;
        f32x4 z = {0.f, 0.f, 0.f, 0.f};
        if (zidx < OUT4) __builtin_nontemporal_store(z, (f32x4*)out + zidx);
    }
    const int lane = tid & 63;
    const float* src;
    unsigned short* dst;
    int unit;
    if (bid < 8192) {                      // X: units = 1024 mb x 32 kc
        unit = bid * 4 + (tid >> 6);
        src = X; dst = A2F;
    } else {                               // W: 1280 units -> 320 blocks
        if (bid == 8192 && tid < 17) slots[tid] = 0ull;   // 16 slots + counter
        unit = (bid - 8192) * 4 + (tid >> 6);
        src = W; dst = B2F;
    }
    int rt = unit >> 5, kc = unit & 31;
    int row = rt * 16 + (lane & 15);
    int col = kc * 32 + ((lane >> 4) << 3);
    const float* p = src + (size_t)row * CC + col;
    float4 v0 = *(const float4*)p;
    float4 v1 = *(const float4*)(p + 4);
    short8 hi;
    hi[0] = (short)bf16_rne(v0.x); hi[1] = (short)bf16_rne(v0.y);
    hi[2] = (short)bf16_rne(v0.z); hi[3] = (short)bf16_rne(v0.w);
    hi[4] = (short)bf16_rne(v1.x); hi[5] = (short)bf16_rne(v1.y);
    hi[6] = (short)bf16_rne(v1.z); hi[7] = (short)bf16_rne(v1.w);
    *(short8*)(dst + (size_t)unit * 512 + lane * 8) = hi;
}

// ------------------- 1-pass bf16 MFMA GEMM + margin argmax + exact refine + scatter ----------
// approx C = Xhi * Whi^T  (dropped-term error sigma ~0.067, margin 2.0 = 15 sigma).
// No LDS, no barriers in the K-loop: A/B frags direct from L2 (fragment-major),
// register-pipelined one iter ahead. Epilogue: block-max -> candidates within
// MARGIN -> cooperative EXACT fp32 dot from X,W -> packed atomicMax. Last block
// (device counter) scatters the 16 codebook rows.
__global__ __launch_bounds__(256, 3)
void gemm_argmax_mfma(const unsigned short* __restrict__ A2F,
                      const unsigned short* __restrict__ B2F,
                      const float* __restrict__ X,
                      const float* __restrict__ W,
                      const float* __restrict__ bias,
                      const float* __restrict__ codebook,
                      float* __restrict__ out,
                      unsigned long long* __restrict__ slots,
                      unsigned int* __restrict__ counter) {
    __shared__ float redf[4];
    __shared__ int cnt_s;
    __shared__ int cand_s[128];
    __shared__ unsigned int done_s;
    __shared__ unsigned long long s16[16];

    const int tid  = threadIdx.x;
    const int lane = tid & 63;
    const int wave = tid >> 6;

    // XCD swizzle: one XCD covers 16 m-tiles x all 5 n-tiles (n fastest) -> A2F L2 reuse.
    const int l   = blockIdx.x;        // 0..639
    const int xcd = l & 7;
    const int w   = l >> 3;
    const int mt  = xcd * 16 + w / 5;
    const int nt  = w % 5;
    const int m0 = mt * 128;
    const int n0 = nt * 128;

    const int wm = (wave >> 1) * 64;
    const int wn = (wave & 1) * 64;

    // frag pointers: tile t, kc stride = 512 shorts (hi-only)
    const unsigned short* Ap[4];
    const unsigned short* Bp[4];
#pragma unroll
    for (int t = 0; t < 4; t++) {
        Ap[t] = A2F + ((size_t)(((m0 + wm) >> 4) + t) * 32) * 512 + lane * 8;
        Bp[t] = B2F + ((size_t)(((n0 + wn) >> 4) + t) * 32) * 512 + lane * 8;
    }

    f32x4 acc[4][4] = {};
    short8 a0[4], b0[4], a1[4], b1[4];

    // prologue: load it=0 frags
#pragma unroll
    for (int t = 0; t < 4; t++) {
        a0[t] = *(const short8*)(Ap[t]);
        b0[t] = *(const short8*)(Bp[t]);
        Ap[t] += 512; Bp[t] += 512;
    }

#define STEP(CURA, CURB, NXTA, NXTB, IT)                                         \
    {                                                                            \
        if ((IT) < 31) {                                                         \
            _Pragma("unroll")                                                    \
            for (int t = 0; t < 4; t++) {                                        \
                NXTA[t] = *(const short8*)(Ap[t]);                               \
                NXTB[t] = *(const short8*)(Bp[t]);                               \
                Ap[t] += 512; Bp[t] += 512;                                      \
            }                                                                    \
        }                                                                        \
        _Pragma("unroll")                                                        \
        for (int ti = 0; ti < 4; ti++)                                           \
            _Pragma("unroll")                                                    \
            for (int tj = 0; tj < 4; tj++)                                       \
                acc[ti][tj] = __builtin_amdgcn_mfma_f32_16x16x32_bf16(           \
                    CURA[ti], CURB[tj], acc[ti][tj], 0, 0, 0);                   \
    }

    for (int it2 = 0; it2 < 16; it2++) {
        STEP(a0, b0, a1, b1, it2 * 2)
        STEP(a1, b1, a0, b0, it2 * 2 + 1)
    }
#undef STEP

    // ---- epilogue: block max of approx logits ----
    // C/D layout (16x16x32): col = lane&15, row = (lane>>4)*4 + reg
    float bias4[4];
#pragma unroll
    for (int tj = 0; tj < 4; tj++) bias4[tj] = bias[n0 + wn + tj * 16 + (lane & 15)];

    float vmax = -3.0e38f;
#pragma unroll
    for (int ti = 0; ti < 4; ti++)
#pragma unroll
        for (int tj = 0; tj < 4; tj++)
#pragma unroll
            for (int r = 0; r < 4; r++)
                vmax = fmaxf(vmax, acc[ti][tj][r] + bias4[tj]);
#pragma unroll
    for (int off = 32; off > 0; off >>= 1)
        vmax = fmaxf(vmax, __shfl_down(vmax, off, 64));
    if (lane == 0) redf[wave] = vmax;
    if (tid == 0) cnt_s = 0;
    __syncthreads();
    float bm = fmaxf(fmaxf(redf[0], redf[1]), fmaxf(redf[2], redf[3]));
    float thresh = bm - MARGIN;

    // ---- collect candidates within MARGIN of block max ----
#pragma unroll
    for (int ti = 0; ti < 4; ti++) {
#pragma unroll
        for (int r = 0; r < 4; r++) {
            int m = m0 + wm + ti * 16 + (lane >> 4) * 4 + r;
#pragma unroll
            for (int tj = 0; tj < 4; tj++) {
                float v = acc[ti][tj][r] + bias4[tj];
                if (v >= thresh) {
                    int n = n0 + wn + tj * 16 + (lane & 15);
                    int idx = atomicAdd(&cnt_s, 1);
                    if (idx < 128) cand_s[idx] = (m << 10) | n;
                }
            }
        }
    }
    __syncthreads();
    int cnt = cnt_s < 128 ? cnt_s : 128;

    // ---- exact fp32 refine of each candidate (cooperative 1024-dot) ----
    for (int i = 0; i < cnt; i++) {
        int mc = cand_s[i] >> 10;
        int nc = cand_s[i] & 1023;
        float4 xv = *(const float4*)(X + (size_t)mc * CC + tid * 4);
        float4 wv = *(const float4*)(W + (size_t)nc * CC + tid * 4);
        float p = xv.x * wv.x + xv.y * wv.y + xv.z * wv.z + xv.w * wv.w;
#pragma unroll
        for (int off = 32; off > 0; off >>= 1) p += __shfl_down(p, off, 64);
        if (lane == 0) redf[wave] = p;
        __syncthreads();
        if (tid == 0) {
            float tot = redf[0] + redf[1] + redf[2] + redf[3] + bias[nc];
            unsigned int c = (unsigned int)((mc & 1023) * KN + nc);
            unsigned long long pk =
                ((unsigned long long)f32_orderable(tot) << 32) |
                (unsigned long long)(~c);
            atomicMax(slots + (mc >> 10), pk);
        }
        __syncthreads();
    }

    if (tid == 0) {
        __threadfence();
        done_s = atomicAdd(counter, 1u);
    }
    __syncthreads();

    // ---- last block scatters the 16 codebook rows ----
    if (done_s == NBLK - 1) {
        if (tid < 16) s16[tid] = atomicAdd(slots + tid, 0ull);   // coherent cross-XCD read
        __syncthreads();
        int rr  = tid >> 4;
        int seg = tid & 15;
        unsigned long long p = s16[rr];
        unsigned int c = ~(unsigned int)(p & 0xFFFFFFFFull);
        int tl = (int)(c / KN);
        int kg = (int)(c % KN);
        int b  = rr >> 1, h = rr & 1;
        int nstar = b * 2048 + h * 1024 + tl;
        int g = kg / EE;
        const float4* src = (const float4*)(codebook + (size_t)kg * DD) + seg * 4;
        float4* dst = (float4*)(out + (size_t)nstar * 512 + (size_t)g * DD) + seg * 4;
#pragma unroll
        for (int j = 0; j < 4; j++) dst[j] = src[j];
    }
}

// ------------------- fallback-only kernels (ws too small; not used in practice) ------------
__global__ __launch_bounds__(256)
void zs_kernel(const unsigned long long* __restrict__ slots,
               const float* __restrict__ codebook,
               float4* __restrict__ out4) {
    int i4 = blockIdx.x * 256 + threadIdx.x;
    int n  = i4 >> 7;
    int c4 = i4 & 127;
    int b  = n >> 11;
    int h  = (n >> 10) & 1;
    unsigned long long p = slots[b * 2 + h];
    unsigned int c = ~(unsigned int)(p & 0xFFFFFFFFull);
    int tl = (int)(c / KN);
    int kg = (int)(c % KN);
    int nstar = b * 2048 + h * 1024 + tl;
    int g = kg / EE;
    float4 v = make_float4(0.f, 0.f, 0.f, 0.f);
    if (n == nstar && (c4 >> 6) == g)
        v = ((const float4*)codebook)[kg * 64 + (c4 & 63)];
    out4[i4] = v;
}

#define BM 128
#define BN 64
#define BK 32
#define LDA (BM + 4)
#define LDB (BN + 4)

__global__ __launch_bounds__(128)
void gemm_argmax_f32(const float* __restrict__ X, const float* __restrict__ W,
                     const float* __restrict__ bias,
                     unsigned long long* __restrict__ slots) {
    __shared__ float Asf[BK][LDA];
    __shared__ float Bsf[BK][LDB];
    const int tid = threadIdx.x;
    const int m0 = blockIdx.y * BM;
    const int n0 = blockIdx.x * BN;
    const int tx = tid & 7, ty = tid >> 3;
    float acc[8][8];
#pragma unroll
    for (int i = 0; i < 8; i++)
#pragma unroll
        for (int j = 0; j < 8; j++) acc[i][j] = 0.0f;
    const int lm = tid >> 3, lk = (tid & 7) * 4;
    const float* Xb = X + (size_t)m0 * CC;
    const float* Wb = W + (size_t)n0 * CC;
    for (int k0 = 0; k0 < CC; k0 += BK) {
#pragma unroll
        for (int r = 0; r < 8; r++) {
            int m = r * 16 + lm;
            float4 v = *(const float4*)(Xb + (size_t)m * CC + k0 + lk);
            Asf[lk + 0][m] = v.x; Asf[lk + 1][m] = v.y; Asf[lk + 2][m] = v.z; Asf[lk + 3][m] = v.w;
        }
#pragma unroll
        for (int r = 0; r < 4; r++) {
            int m = r * 16 + lm;
            float4 v = *(const float4*)(Wb + (size_t)m * CC + k0 + lk);
            Bsf[lk + 0][m] = v.x; Bsf[lk + 1][m] = v.y; Bsf[lk + 2][m] = v.z; Bsf[lk + 3][m] = v.w;
        }
        __syncthreads();
#pragma unroll
        for (int kk = 0; kk < BK; kk++) {
            float4 A0 = *(const float4*)&Asf[kk][ty * 8];
            float4 A1 = *(const float4*)&Asf[kk][ty * 8 + 4];
            float4 B0 = *(const float4*)&Bsf[kk][tx * 8];
            float4 B1 = *(const float4*)&Bsf[kk][tx * 8 + 4];
            float a[8] = {A0.x, A0.y, A0.z, A0.w, A1.x, A1.y, A1.z, A1.w};
            float b[8] = {B0.x, B0.y, B0.z, B0.w, B1.x, B1.y, B1.z, B1.w};
#pragma unroll
            for (int i = 0; i < 8; i++)
#pragma unroll
                for (int j = 0; j < 8; j++) acc[i][j] = fmaf(a[i], b[j], acc[i][j]);
        }
        __syncthreads();
    }
    unsigned long long best = 0ull;
#pragma unroll
    for (int i = 0; i < 8; i++) {
        int mg = m0 + ty * 8 + i;
        int tl = mg & 1023;
#pragma unroll
        for (int j = 0; j < 8; j++) {
            int kg = n0 + tx * 8 + j;
            float v = acc[i][j] + bias[kg];
            unsigned int c = (unsigned int)(tl * KN + kg);
            unsigned long long p = ((unsigned long long)f32_orderable(v) << 32) |
                                   (unsigned long long)(~c);
            if (p > best) best = p;
        }
    }
#pragma unroll
    for (int off = 32; off > 0; off >>= 1) {
        unsigned long long o = __shfl_down(best, off, 64);
        if (o > best) best = o;
    }
    __shared__ unsigned long long red2[2];
    if ((tid & 63) == 0) red2[tid >> 6] = best;
    __syncthreads();
    if (tid == 0) {
        unsigned long long b0 = red2[0], b1 = red2[1];
        atomicMax(slots + (m0 >> 10), b0 > b1 ? b0 : b1);
    }
}

extern "C" void kernel_launch(void* const* d_in, const int* in_sizes, int n_in,
                              void* d_out, int out_size, void* d_ws, size_t ws_size,
                              hipStream_t stream) {
    const float* X        = (const float*)d_in[0];  // (8,2048,1024)
    const float* W        = (const float*)d_in[1];  // (640,1024)
    const float* bias     = (const float*)d_in[2];  // (640,)
    const float* codebook = (const float*)d_in[3];  // (640,256)
    float* out = (float*)d_out;                     // (8,2048,512) fp32

    unsigned long long* slots = (unsigned long long*)d_ws;   // [0..15] slots, [16] counter
    unsigned int* counter = (unsigned int*)(slots + 16);
    const size_t A_off   = 256;
    const size_t A_bytes = (size_t)MTOT * CC * 2;       // 33,554,432 (hi-only frag-major)
    const size_t B_off   = A_off + A_bytes;
    const size_t B_bytes = (size_t)KN * CC * 2;         // 1,310,720
    const size_t need = B_off + B_bytes;

    if (ws_size >= need) {
        unsigned short* A2F = (unsigned short*)((char*)d_ws + A_off);
        unsigned short* B2F = (unsigned short*)((char*)d_ws + B_off);
        hipLaunchKernelGGL(convert_kernel, dim3(8192 + 320), dim3(256), 0, stream,
                           X, W, A2F, B2F, slots, out);
        hipLaunchKernelGGL(gemm_argmax_mfma, dim3(NBLK), dim3(256), 0, stream,
                           A2F, B2F, X, W, bias, codebook, out, slots, counter);
    } else {
        hipLaunchKernelGGL(init_slots_kernel, dim3(1), dim3(64), 0, stream, slots);
        hipLaunchKernelGGL(gemm_argmax_f32, dim3(KN / BN, MTOT / BM), dim3(128), 0, stream,
                           X, W, bias, slots);
        hipLaunchKernelGGL(zs_kernel, dim3(OUT4 / 256), dim3(256), 0, stream,
                           slots, codebook, (float4*)out);
    }
}